// Round 12
// baseline (492.501 us; speedup 1.0000x reference)
//
#include <hip/hip_runtime.h>

// Problem constants (fixed by the reference setup)
constexpr int NN = 100000;   // nodes
constexpr int RR = 8;        // relations
constexpr int BB = 4;        // bases
constexpr int DD = 64;       // feature dim
constexpr int EE = 2000000;  // edges
constexpr int PP = 500000;   // pairs
constexpr int CAP = 64;      // fixed per-node bucket capacity (deg ~ Poisson(20))

constexpr int NBIN = 196;      // ceil(100000 / 512) node-range bins
constexpr int BINCAP = 16384;  // per-bin record cap (expect ~10.2k, >60 sigma slack)
constexpr int EPB = 4096;      // edges per bin_kernel block (16/thread)

constexpr int YSTRIDE = 264;   // ys row pad: 264 shorts = 528 B -> 4-bank row shift

typedef __attribute__((ext_vector_type(8))) short short8;      // 8 bf16 MFMA frag
typedef __attribute__((ext_vector_type(4))) unsigned short ushort4v;
typedef __attribute__((ext_vector_type(4))) float f32x4;

// ---------------------------------------------------------------------------
// bf16 helpers (RNE)
__device__ __forceinline__ unsigned short f2bf(float f) {
    unsigned u = __float_as_uint(f);
    u += 0x7FFFu + ((u >> 16) & 1u);
    return (unsigned short)(u >> 16);
}
__device__ __forceinline__ float bf2f(unsigned short b) {
    return __uint_as_float(((unsigned)b) << 16);
}

// split 8 consecutive f32 at p into hi/lo bf16 frags
__device__ __forceinline__ void split8(const float* __restrict__ p, short8& h, short8& l) {
    float4 a = *reinterpret_cast<const float4*>(p);
    float4 b = *reinterpret_cast<const float4*>(p + 4);
    unsigned short h0 = f2bf(a.x), h1 = f2bf(a.y), h2 = f2bf(a.z), h3 = f2bf(a.w);
    unsigned short h4 = f2bf(b.x), h5 = f2bf(b.y), h6 = f2bf(b.z), h7 = f2bf(b.w);
    h = (short8){(short)h0, (short)h1, (short)h2, (short)h3,
                 (short)h4, (short)h5, (short)h6, (short)h7};
    l = (short8){(short)f2bf(a.x - bf2f(h0)), (short)f2bf(a.y - bf2f(h1)),
                 (short)f2bf(a.z - bf2f(h2)), (short)f2bf(a.w - bf2f(h3)),
                 (short)f2bf(b.x - bf2f(h4)), (short)f2bf(b.y - bf2f(h5)),
                 (short)f2bf(b.z - bf2f(h6)), (short)f2bf(b.w - bf2f(h7))};
}

// f32 -> bf16 plane copy (vectorized)
__global__ void tobf16_kernel(const float* __restrict__ in, unsigned short* __restrict__ out,
                              int n4) {
    int i = blockIdx.x * blockDim.x + threadIdx.x;
    if (i >= n4) return;
    float4 v = reinterpret_cast<const float4*>(in)[i];
    ushort4v o;
    o.x = f2bf(v.x); o.y = f2bf(v.y); o.z = f2bf(v.z); o.w = f2bf(v.w);
    reinterpret_cast<ushort4v*>(out)[i] = o;
}

// ---------------------------------------------------------------------------
// Phase 1: partition edges into 196 bins by dst>>9. Record = src | et<<17 |
// dstlocal<<20 (29 bits, 4 B). LDS histogram -> one global atomic per bin.
__global__ void bin_kernel(const int* __restrict__ src, const int* __restrict__ dst,
                           const int* __restrict__ et, int* __restrict__ bin_cursor,
                           unsigned* __restrict__ ebin) {
    __shared__ int lcount[NBIN];
    __shared__ int lbase[NBIN];
    int tid = threadIdx.x;
    for (int i = tid; i < NBIN; i += 256) lcount[i] = 0;
    __syncthreads();

    int e0 = blockIdx.x * EPB;
    unsigned rec[16];
    int rnk[16];
    int bn[16];
#pragma unroll
    for (int j = 0; j < 16; ++j) {
        int e = e0 + j * 256 + tid;
        if (e < EE) {
            int d = dst[e];
            int b = d >> 9;
            bn[j] = b;
            rec[j] = (unsigned)src[e] | ((unsigned)et[e] << 17) | ((unsigned)(d & 511) << 20);
            rnk[j] = atomicAdd(&lcount[b], 1);
        } else {
            rnk[j] = -1;
        }
    }
    __syncthreads();
    for (int i = tid; i < NBIN; i += 256) lbase[i] = atomicAdd(&bin_cursor[i], lcount[i]);
    __syncthreads();
#pragma unroll
    for (int j = 0; j < 16; ++j) {
        if (rnk[j] >= 0) {
            int pos = lbase[bn[j]] + rnk[j];
            if (pos < BINCAP) ebin[(size_t)bn[j] * BINCAP + pos] = rec[j];
        }
    }
}

// Phase 2: ONE block per bin. Ranks via LDS atomics; the block's 128 KB epack
// region stays L2-resident. cnt written coalesced from LDS at the end.
__global__ __launch_bounds__(1024) void bucket_kernel(
    const unsigned* __restrict__ ebin, const int* __restrict__ bin_cursor,
    int* __restrict__ cnt, unsigned* __restrict__ epack) {
    __shared__ int lcnt[512];
    int bin = blockIdx.x;
    int tid = threadIdx.x;
    for (int i = tid; i < 512; i += 1024) lcnt[i] = 0;
    __syncthreads();

    int m = bin_cursor[bin];
    if (m > BINCAP) m = BINCAP;
    const unsigned* base = ebin + (size_t)bin * BINCAP;
    int nodebase = bin << 9;

    for (int i = tid; i < m; i += 1024) {
        unsigned rec = base[i];
        int dl = rec >> 20;
        int r = atomicAdd(&lcnt[dl], 1);
        if (r < CAP)
            epack[(size_t)(nodebase + dl) * CAP + r] = rec & 0xFFFFFu;  // src | et<<17
    }
    __syncthreads();
    for (int i = tid; i < 512; i += 1024) {
        int n = nodebase + i;
        if (n < NN) cnt[n] = lcnt[i];
    }
}

// ---------------------------------------------------------------------------
// stage B tile transposed: src is [64 k][64 n] row-major -> LDS Bt[n][k], hi/lo
__device__ __forceinline__ void stage_b(const float* __restrict__ src, int tid,
                                        unsigned short* Bh, unsigned short* Bl) {
#pragma unroll
    for (int j = 0; j < 4; ++j) {
        int e4 = j * 256 + tid;
        int r = e4 >> 4;           // k index
        int c4 = (e4 & 15) << 2;   // n base
        float4 v = *reinterpret_cast<const float4*>(src + r * 64 + c4);
        unsigned short h0 = f2bf(v.x), h1 = f2bf(v.y), h2 = f2bf(v.z), h3 = f2bf(v.w);
        Bh[(c4 + 0) * 72 + r] = h0;
        Bh[(c4 + 1) * 72 + r] = h1;
        Bh[(c4 + 2) * 72 + r] = h2;
        Bh[(c4 + 3) * 72 + r] = h3;
        Bl[(c4 + 0) * 72 + r] = f2bf(v.x - bf2f(h0));
        Bl[(c4 + 1) * 72 + r] = f2bf(v.y - bf2f(h1));
        Bl[(c4 + 2) * 72 + r] = f2bf(v.z - bf2f(h2));
        Bl[(c4 + 3) * 72 + r] = f2bf(v.w - bf2f(h3));
    }
}

// K=64 chunk, A frags in registers, full bf16x3 (hi/lo): 6 MFMAs per n-tile
#define MFMA_X(AH0, AH1, AL0, AL1, ACC)                                          \
    {                                                                            \
        _Pragma("unroll")                                                        \
        for (int t = 0; t < 4; ++t) {                                            \
            int bc = t * 16 + ln15;                                              \
            short8 bh0 = *reinterpret_cast<const short8*>(&Bh[bc * 72 + kb]);    \
            short8 bh1 = *reinterpret_cast<const short8*>(&Bh[bc * 72 + 32 + kb]);\
            short8 bl0 = *reinterpret_cast<const short8*>(&Bl[bc * 72 + kb]);    \
            short8 bl1 = *reinterpret_cast<const short8*>(&Bl[bc * 72 + 32 + kb]);\
            ACC[t] = __builtin_amdgcn_mfma_f32_16x16x32_bf16(AH0, bh0, ACC[t], 0, 0, 0); \
            ACC[t] = __builtin_amdgcn_mfma_f32_16x16x32_bf16(AH1, bh1, ACC[t], 0, 0, 0); \
            ACC[t] = __builtin_amdgcn_mfma_f32_16x16x32_bf16(AH0, bl0, ACC[t], 0, 0, 0); \
            ACC[t] = __builtin_amdgcn_mfma_f32_16x16x32_bf16(AH1, bl1, ACC[t], 0, 0, 0); \
            ACC[t] = __builtin_amdgcn_mfma_f32_16x16x32_bf16(AL0, bh0, ACC[t], 0, 0, 0); \
            ACC[t] = __builtin_amdgcn_mfma_f32_16x16x32_bf16(AL1, bh1, ACC[t], 0, 0, 0); \
        }                                                                        \
    }

// K=64 chunk, A = ys LDS chunk C (hi only): 4 MFMAs per n-tile
#define MFMA_Y(C, ACC)                                                           \
    {                                                                            \
        short8 ah0 = *reinterpret_cast<const short8*>(&ys[arow * YSTRIDE + (C) * 64 + kb]);      \
        short8 ah1 = *reinterpret_cast<const short8*>(&ys[arow * YSTRIDE + (C) * 64 + 32 + kb]); \
        _Pragma("unroll")                                                        \
        for (int t = 0; t < 4; ++t) {                                            \
            int bc = t * 16 + ln15;                                              \
            short8 bh0 = *reinterpret_cast<const short8*>(&Bh[bc * 72 + kb]);    \
            short8 bh1 = *reinterpret_cast<const short8*>(&Bh[bc * 72 + 32 + kb]);\
            short8 bl0 = *reinterpret_cast<const short8*>(&Bl[bc * 72 + kb]);    \
            short8 bl1 = *reinterpret_cast<const short8*>(&Bl[bc * 72 + 32 + kb]);\
            ACC[t] = __builtin_amdgcn_mfma_f32_16x16x32_bf16(ah0, bh0, ACC[t], 0, 0, 0); \
            ACC[t] = __builtin_amdgcn_mfma_f32_16x16x32_bf16(ah1, bh1, ACC[t], 0, 0, 0); \
            ACC[t] = __builtin_amdgcn_mfma_f32_16x16x32_bf16(ah0, bl0, ACC[t], 0, 0, 0); \
            ACC[t] = __builtin_amdgcn_mfma_f32_16x16x32_bf16(ah1, bl1, ACC[t], 0, 0, 0); \
        }                                                                        \
    }

// K=64 chunk, A = Zh/Zl LDS (72-pad), full bf16x3: 6 MFMAs per n-tile
#define MFMA_Z(ACC)                                                              \
    {                                                                            \
        short8 ah0 = *reinterpret_cast<const short8*>(&Zh[arow * 72 + kb]);      \
        short8 ah1 = *reinterpret_cast<const short8*>(&Zh[arow * 72 + 32 + kb]); \
        short8 al0 = *reinterpret_cast<const short8*>(&Zl[arow * 72 + kb]);      \
        short8 al1 = *reinterpret_cast<const short8*>(&Zl[arow * 72 + 32 + kb]); \
        MFMA_X(ah0, ah1, al0, al1, ACC)                                          \
    }

// ---------------------------------------------------------------------------
// Fused per-layer kernel: gather-aggregate into LDS ys, then MFMA transform.
// Block = 256 threads = 4 waves; 64 nodes/block (16 nodes/wave, sequential).
// XSPLIT=0: root chunk A from f32 xf. XSPLIT=1: from bf16 planes xh/xl.
// PROJ=0: out = bf16 hi/lo planes (o1,o2), optional ReLU.
// PROJ=1: z -> W1 halves, o1=ha, o2=hb.
template <int RELU, int PROJ, int XSPLIT>
__global__ __launch_bounds__(256) void rgcn_layer(
    const unsigned short* __restrict__ xg,  // gather source (bf16 hi plane)
    const float* __restrict__ xf,           // layer-1 root source (f32)
    const unsigned short* __restrict__ xh, const unsigned short* __restrict__ xl,
    const unsigned* __restrict__ epack, const int* __restrict__ cnt,
    const float* __restrict__ comp, const float* __restrict__ basis,
    const float* __restrict__ root, const float* __restrict__ bias,
    const float* __restrict__ W1,
    unsigned short* __restrict__ o1, unsigned short* __restrict__ o2) {
    __shared__ unsigned short ys[64 * YSTRIDE];          // 33.8 KB basis-coords tile
    __shared__ unsigned short Bh[64 * 72], Bl[64 * 72];  // 18.4 KB weight tile
    __shared__ float wlds[4 * 32];

    int tid = threadIdx.x;
    int lane = tid & 63;
    int wid = tid >> 6;
    int ln15 = lane & 15;
    int blockM = blockIdx.x * 64;
    int wr = wid * 16;
    int arow = wr + ln15;
    int kb = (lane >> 4) * 8;
    int half = lane >> 5;
    int fl = lane & 31;

    // stage root B-tile up front (Bh/Bl fresh; barrier below covers visibility)
    stage_b(root, tid, Bh, Bl);

    // ---- gather-aggregate phase: 16 nodes per wave -> ys rows ----
    unsigned* ys32 = reinterpret_cast<unsigned*>(ys);
    for (int j = 0; j < 16; ++j) {
        int nl = wr + j;
        int n = blockM + nl;
        int m = (n < NN) ? cnt[n] : 0;
        if (m > CAP) m = CAP;

        unsigned pl = (lane < m) ? epack[(size_t)n * CAP + lane] : 0u;
        int et_l = (int)(pl >> 17);

        int cr0 = __popcll(__ballot((lane < m) && (et_l == 0)));
        int cr1 = __popcll(__ballot((lane < m) && (et_l == 1)));
        int cr2 = __popcll(__ballot((lane < m) && (et_l == 2)));
        int cr3 = __popcll(__ballot((lane < m) && (et_l == 3)));
        int cr4 = __popcll(__ballot((lane < m) && (et_l == 4)));
        int cr5 = __popcll(__ballot((lane < m) && (et_l == 5)));
        int cr6 = __popcll(__ballot((lane < m) && (et_l == 6)));
        int cr7 = __popcll(__ballot((lane < m) && (et_l == 7)));

        if (lane < 32) {
            int r = lane >> 2;
            int myc = cr0;
            myc = (r == 1) ? cr1 : myc;
            myc = (r == 2) ? cr2 : myc;
            myc = (r == 3) ? cr3 : myc;
            myc = (r == 4) ? cr4 : myc;
            myc = (r == 5) ? cr5 : myc;
            myc = (r == 6) ? cr6 : myc;
            myc = (r == 7) ? cr7 : myc;
            wlds[wid * 32 + lane] = comp[lane] / fmaxf((float)myc, 1.f);
        }
        // wave-synchronous LDS write->read (compiler emits lgkmcnt wait)

        float a0x = 0.f, a0y = 0.f, a1x = 0.f, a1y = 0.f;
        float a2x = 0.f, a2y = 0.f, a3x = 0.f, a3y = 0.f;

        int k = 0;
        for (; k + 4 <= m; k += 4) {
            unsigned pA = __shfl(pl, k + half);
            unsigned pB = __shfl(pl, k + 2 + half);
            unsigned rA = *reinterpret_cast<const unsigned*>(
                xg + (size_t)(pA & 0x1FFFFu) * 64 + fl * 2);
            unsigned rB = *reinterpret_cast<const unsigned*>(
                xg + (size_t)(pB & 0x1FFFFu) * 64 + fl * 2);
            float4 wA = *reinterpret_cast<const float4*>(&wlds[wid * 32 + (pA >> 17) * 4]);
            float4 wB = *reinterpret_cast<const float4*>(&wlds[wid * 32 + (pB >> 17) * 4]);
            float rAx = bf2f((unsigned short)(rA & 0xFFFF));
            float rAy = bf2f((unsigned short)(rA >> 16));
            float rBx = bf2f((unsigned short)(rB & 0xFFFF));
            float rBy = bf2f((unsigned short)(rB >> 16));
            a0x = fmaf(wA.x, rAx, a0x); a0y = fmaf(wA.x, rAy, a0y);
            a1x = fmaf(wA.y, rAx, a1x); a1y = fmaf(wA.y, rAy, a1y);
            a2x = fmaf(wA.z, rAx, a2x); a2y = fmaf(wA.z, rAy, a2y);
            a3x = fmaf(wA.w, rAx, a3x); a3y = fmaf(wA.w, rAy, a3y);
            a0x = fmaf(wB.x, rBx, a0x); a0y = fmaf(wB.x, rBy, a0y);
            a1x = fmaf(wB.y, rBx, a1x); a1y = fmaf(wB.y, rBy, a1y);
            a2x = fmaf(wB.z, rBx, a2x); a2y = fmaf(wB.z, rBy, a2y);
            a3x = fmaf(wB.w, rBx, a3x); a3y = fmaf(wB.w, rBy, a3y);
        }
        for (; k < m; k += 2) {
            int ki = k + half;
            int kc = (ki < m) ? ki : k;
            float sc = (ki < m) ? 1.f : 0.f;
            unsigned p = __shfl(pl, kc);
            unsigned rv = *reinterpret_cast<const unsigned*>(
                xg + (size_t)(p & 0x1FFFFu) * 64 + fl * 2);
            float4 wv = *reinterpret_cast<const float4*>(&wlds[wid * 32 + (p >> 17) * 4]);
            float rx = bf2f((unsigned short)(rv & 0xFFFF)) * sc;
            float ry = bf2f((unsigned short)(rv >> 16)) * sc;
            a0x = fmaf(wv.x, rx, a0x); a0y = fmaf(wv.x, ry, a0y);
            a1x = fmaf(wv.y, rx, a1x); a1y = fmaf(wv.y, ry, a1y);
            a2x = fmaf(wv.z, rx, a2x); a2y = fmaf(wv.z, ry, a2y);
            a3x = fmaf(wv.w, rx, a3x); a3y = fmaf(wv.w, ry, a3y);
        }

        a0x += __shfl_xor(a0x, 32); a0y += __shfl_xor(a0y, 32);
        a1x += __shfl_xor(a1x, 32); a1y += __shfl_xor(a1y, 32);
        a2x += __shfl_xor(a2x, 32); a2y += __shfl_xor(a2y, 32);
        a3x += __shfl_xor(a3x, 32); a3y += __shfl_xor(a3y, 32);

        float sLx = half ? a2x : a0x, sLy = half ? a2y : a0y;
        float sHx = half ? a3x : a1x, sHy = half ? a3y : a1y;
        unsigned pL = (unsigned)f2bf(sLx) | ((unsigned)f2bf(sLy) << 16);
        unsigned pH = (unsigned)f2bf(sHx) | ((unsigned)f2bf(sHy) << 16);
        ys32[nl * (YSTRIDE / 2) + (half * 2) * 32 + fl] = pL;
        ys32[nl * (YSTRIDE / 2) + (half * 2 + 1) * 32 + fl] = pH;
    }

    // ---- root-chunk A frags direct from global (no LDS staging) ----
    short8 xh0, xh1, xl0, xl1;
    {
        int gr = blockM + arow;
        if (gr > NN - 1) gr = NN - 1;
        if (XSPLIT) {
            xh0 = *reinterpret_cast<const short8*>(xh + (size_t)gr * 64 + kb);
            xh1 = *reinterpret_cast<const short8*>(xh + (size_t)gr * 64 + 32 + kb);
            xl0 = *reinterpret_cast<const short8*>(xl + (size_t)gr * 64 + kb);
            xl1 = *reinterpret_cast<const short8*>(xl + (size_t)gr * 64 + 32 + kb);
        } else {
            split8(xf + (size_t)gr * 64 + kb, xh0, xl0);
            split8(xf + (size_t)gr * 64 + 32 + kb, xh1, xl1);
        }
    }

    __syncthreads();  // ys + Bh/Bl visible

    f32x4 acc[4];
#pragma unroll
    for (int t = 0; t < 4; ++t) {
        float bv = bias[t * 16 + ln15];
        acc[t] = (f32x4){bv, bv, bv, bv};
    }

    MFMA_X(xh0, xh1, xl0, xl1, acc)  // x @ root

#pragma unroll
    for (int c = 0; c < 4; ++c) {    // y_b @ basis_b
        __syncthreads();
        stage_b(basis + (size_t)c * 4096, tid, Bh, Bl);
        __syncthreads();
        MFMA_Y(c, acc)
    }

    if (!PROJ) {
#pragma unroll
        for (int t = 0; t < 4; ++t) {
            int cc = t * 16 + ln15;
#pragma unroll
            for (int i = 0; i < 4; ++i) {
                int gr = blockM + wr + (lane >> 4) * 4 + i;
                if (gr < NN) {
                    float v = acc[t][i];
                    if (RELU) v = fmaxf(v, 0.f);
                    unsigned short h = f2bf(v);
                    o1[(size_t)gr * 64 + cc] = h;
                    o2[(size_t)gr * 64 + cc] = f2bf(v - bf2f(h));
                }
            }
        }
    } else {
        // z hi/lo staged into the now-dead ys region
        unsigned short* Zh = ys;
        unsigned short* Zl = ys + 64 * 72;
        __syncthreads();  // all waves done reading ys & Bh/Bl
#pragma unroll
        for (int t = 0; t < 4; ++t) {
            int cc = t * 16 + ln15;
#pragma unroll
            for (int i = 0; i < 4; ++i) {
                int r = wr + (lane >> 4) * 4 + i;
                float v = acc[t][i];
                unsigned short h = f2bf(v);
                Zh[r * 72 + cc] = h;
                Zl[r * 72 + cc] = f2bf(v - bf2f(h));
            }
        }
        stage_b(W1, tid, Bh, Bl);  // ha half
        __syncthreads();
        f32x4 acc2[4];
#pragma unroll
        for (int t = 0; t < 4; ++t) acc2[t] = (f32x4){0.f, 0.f, 0.f, 0.f};
        MFMA_Z(acc2)
#pragma unroll
        for (int t = 0; t < 4; ++t) {
            int cc = t * 16 + ln15;
#pragma unroll
            for (int i = 0; i < 4; ++i) {
                int gr = blockM + wr + (lane >> 4) * 4 + i;
                if (gr < NN) o1[(size_t)gr * 64 + cc] = f2bf(acc2[t][i]);
            }
        }
        __syncthreads();
        stage_b(W1 + 64 * 64, tid, Bh, Bl);  // hb half
        __syncthreads();
#pragma unroll
        for (int t = 0; t < 4; ++t) acc2[t] = (f32x4){0.f, 0.f, 0.f, 0.f};
        MFMA_Z(acc2)
#pragma unroll
        for (int t = 0; t < 4; ++t) {
            int cc = t * 16 + ln15;
#pragma unroll
            for (int i = 0; i < 4; ++i) {
                int gr = blockM + wr + (lane >> 4) * 4 + i;
                if (gr < NN) o2[(size_t)gr * 64 + cc] = f2bf(acc2[t][i]);
            }
        }
    }
}

// ---------------------------------------------------------------------------
// decode: 8 pairs per wave. lane = (pg = lane>>3, fg = lane&7);
// lane loads uint4 (8 bf16) of ha[a] and hb[b] at features fg*8..fg*8+7,
// per-lane partial dot, 3-step shfl reduce over the 8 fg lanes.
__global__ void decode_kernel(const int* __restrict__ pairs,
                              const unsigned short* __restrict__ ha,
                              const unsigned short* __restrict__ hb,
                              const float* __restrict__ b1, const float* __restrict__ W2,
                              const float* __restrict__ b2, float* __restrict__ out) {
    int lane = threadIdx.x & 63;
    int wid = threadIdx.x >> 6;
    int wpair0 = (blockIdx.x * 4 + wid) * 8;  // first pair of this wave
    int pg = lane >> 3;
    int fg = lane & 7;

    int pv = 0;
    if (lane < 16) pv = pairs[(size_t)wpair0 * 2 + lane];
    int a = __shfl(pv, pg * 2);
    int b = __shfl(pv, pg * 2 + 1);

    const float4* b1p = reinterpret_cast<const float4*>(b1 + fg * 8);
    float4 b1a = b1p[0], b1b = b1p[1];
    const float4* w2p = reinterpret_cast<const float4*>(W2 + fg * 8);
    float4 w2a = w2p[0], w2b = w2p[1];

    uint4 hau = *reinterpret_cast<const uint4*>(ha + (size_t)a * 64 + fg * 8);
    uint4 hbu = *reinterpret_cast<const uint4*>(hb + (size_t)b * 64 + fg * 8);

    float s = 0.f;
    s += fmaxf(bf2f((unsigned short)(hau.x & 0xFFFF)) + bf2f((unsigned short)(hbu.x & 0xFFFF)) + b1a.x, 0.f) * w2a.x;
    s += fmaxf(bf2f((unsigned short)(hau.x >> 16))    + bf2f((unsigned short)(hbu.x >> 16))    + b1a.y, 0.f) * w2a.y;
    s += fmaxf(bf2f((unsigned short)(hau.y & 0xFFFF)) + bf2f((unsigned short)(hbu.y & 0xFFFF)) + b1a.z, 0.f) * w2a.z;
    s += fmaxf(bf2f((unsigned short)(hau.y >> 16))    + bf2f((unsigned short)(hbu.y >> 16))    + b1a.w, 0.f) * w2a.w;
    s += fmaxf(bf2f((unsigned short)(hau.z & 0xFFFF)) + bf2f((unsigned short)(hbu.z & 0xFFFF)) + b1b.x, 0.f) * w2b.x;
    s += fmaxf(bf2f((unsigned short)(hau.z >> 16))    + bf2f((unsigned short)(hbu.z >> 16))    + b1b.y, 0.f) * w2b.y;
    s += fmaxf(bf2f((unsigned short)(hau.w & 0xFFFF)) + bf2f((unsigned short)(hbu.w & 0xFFFF)) + b1b.z, 0.f) * w2b.z;
    s += fmaxf(bf2f((unsigned short)(hau.w >> 16))    + bf2f((unsigned short)(hbu.w >> 16))    + b1b.w, 0.f) * w2b.w;

    s += __shfl_xor(s, 1);
    s += __shfl_xor(s, 2);
    s += __shfl_xor(s, 4);
    if (fg == 0) out[wpair0 + pg] = s + b2[0];
}

// ---------------------------------------------------------------------------
static inline char* align64(char* p) {
    return (char*)(((uintptr_t)p + 63) & ~(uintptr_t)63);
}

extern "C" void kernel_launch(void* const* d_in, const int* in_sizes, int n_in,
                              void* d_out, int out_size, void* d_ws, size_t ws_size,
                              hipStream_t stream) {
    const int* edge_index = (const int*)d_in[0];
    const int* edge_type  = (const int*)d_in[1];
    const int* edge_pairs = (const int*)d_in[2];
    const float* node_emb = (const float*)d_in[3];
    const float* comp1 = (const float*)d_in[4];
    const float* basis1 = (const float*)d_in[5];
    const float* root1 = (const float*)d_in[6];
    const float* bias1 = (const float*)d_in[7];
    const float* comp2 = (const float*)d_in[8];
    const float* basis2 = (const float*)d_in[9];
    const float* root2 = (const float*)d_in[10];
    const float* bias2 = (const float*)d_in[11];
    const float* W1 = (const float*)d_in[12];
    const float* b1 = (const float*)d_in[13];
    const float* W2 = (const float*)d_in[14];
    const float* b2 = (const float*)d_in[15];

    const int* src = edge_index;
    const int* dst = edge_index + EE;

    // workspace layout (all regions 64B-aligned)
    char* w = (char*)d_ws;
    int* bin_cursor = (int*)w;            w = align64(w + sizeof(int) * NBIN);
    int* cnt        = (int*)w;            w = align64(w + sizeof(int) * NN);
    unsigned* ebin  = (unsigned*)w;       w = align64(w + sizeof(unsigned) * (size_t)NBIN * BINCAP);
    unsigned* epack = (unsigned*)w;       w = align64(w + sizeof(unsigned) * (size_t)NN * CAP);
    unsigned short* xemb = (unsigned short*)w; w = align64(w + sizeof(short) * (size_t)NN * 64);
    unsigned short* x1h  = (unsigned short*)w; w = align64(w + sizeof(short) * (size_t)NN * 64);
    unsigned short* x1l  = (unsigned short*)w; w = align64(w + sizeof(short) * (size_t)NN * 64);
    unsigned short* hab  = (unsigned short*)w; w = align64(w + sizeof(short) * (size_t)NN * 64);
    unsigned short* hbb  = (unsigned short*)w; w = align64(w + sizeof(short) * (size_t)NN * 64);

    // ---- CSR build: bin by dst>>9, then one block per bin with LDS ranks ----
    hipMemsetAsync(bin_cursor, 0, sizeof(int) * NBIN, stream);
    bin_kernel<<<(EE + EPB - 1) / EPB, 256, 0, stream>>>(src, dst, edge_type, bin_cursor, ebin);
    bucket_kernel<<<NBIN, 1024, 0, stream>>>(ebin, bin_cursor, cnt, epack);
    tobf16_kernel<<<(NN * 16 + 255) / 256, 256, 0, stream>>>(node_emb, xemb, NN * 16);

    // ---- layer 1 (fused aggregate+transform): node_emb -> x1 hi/lo (relu) ----
    rgcn_layer<1, 0, 0><<<(NN + 63) / 64, 256, 0, stream>>>(
        xemb, node_emb, nullptr, nullptr, epack, cnt, comp1, basis1, root1, bias1,
        nullptr, x1h, x1l);

    // ---- layer 2 (fused, + decoder projection): x1 -> ha/hb (bf16) ----
    rgcn_layer<0, 1, 1><<<(NN + 63) / 64, 256, 0, stream>>>(
        x1h, nullptr, x1h, x1l, epack, cnt, comp2, basis2, root2, bias2,
        W1, hab, hbb);

    // ---- decoder ----
    decode_kernel<<<PP / 32, 256, 0, stream>>>(edge_pairs, hab, hbb, b1, W2, b2, (float*)d_out);
}

// Round 13
// 351.918 us; speedup vs baseline: 1.3995x; 1.3995x over previous
//
#include <hip/hip_runtime.h>

// Problem constants (fixed by the reference setup)
constexpr int NN = 100000;   // nodes
constexpr int RR = 8;        // relations
constexpr int BB = 4;        // bases
constexpr int DD = 64;       // feature dim
constexpr int EE = 2000000;  // edges
constexpr int PP = 500000;   // pairs
constexpr int CAP = 64;      // fixed per-node bucket capacity (deg ~ Poisson(20))

constexpr int NBIN = 196;      // ceil(100000 / 512) node-range bins
constexpr int BINCAP = 16384;  // per-bin record cap (expect ~10.2k, >60 sigma slack)
constexpr int EPB = 4096;      // edges per bin_kernel block (16/thread)

constexpr int YSTRIDE = 264;   // ys row pad (shorts): 528 B -> 4-bank row shift

typedef __attribute__((ext_vector_type(8))) short short8;      // 8 bf16 MFMA frag
typedef __attribute__((ext_vector_type(4))) unsigned short ushort4v;
typedef __attribute__((ext_vector_type(4))) float f32x4;

// ---------------------------------------------------------------------------
// bf16 helpers (RNE)
__device__ __forceinline__ unsigned short f2bf(float f) {
    unsigned u = __float_as_uint(f);
    u += 0x7FFFu + ((u >> 16) & 1u);
    return (unsigned short)(u >> 16);
}
__device__ __forceinline__ float bf2f(unsigned short b) {
    return __uint_as_float(((unsigned)b) << 16);
}

// split 8 consecutive f32 at p into hi/lo bf16 frags
__device__ __forceinline__ void split8(const float* __restrict__ p, short8& h, short8& l) {
    float4 a = *reinterpret_cast<const float4*>(p);
    float4 b = *reinterpret_cast<const float4*>(p + 4);
    unsigned short h0 = f2bf(a.x), h1 = f2bf(a.y), h2 = f2bf(a.z), h3 = f2bf(a.w);
    unsigned short h4 = f2bf(b.x), h5 = f2bf(b.y), h6 = f2bf(b.z), h7 = f2bf(b.w);
    h = (short8){(short)h0, (short)h1, (short)h2, (short)h3,
                 (short)h4, (short)h5, (short)h6, (short)h7};
    l = (short8){(short)f2bf(a.x - bf2f(h0)), (short)f2bf(a.y - bf2f(h1)),
                 (short)f2bf(a.z - bf2f(h2)), (short)f2bf(a.w - bf2f(h3)),
                 (short)f2bf(b.x - bf2f(h4)), (short)f2bf(b.y - bf2f(h5)),
                 (short)f2bf(b.z - bf2f(h6)), (short)f2bf(b.w - bf2f(h7))};
}

__device__ __forceinline__ void load_bfrag(const unsigned short* __restrict__ p,
                                           short8& b0, short8& b1) {
    b0 = *reinterpret_cast<const short8*>(p);
    b1 = *reinterpret_cast<const short8*>(p + 32);
}

// f32 -> bf16 plane copy (vectorized)
__global__ void tobf16_kernel(const float* __restrict__ in, unsigned short* __restrict__ out,
                              int n4) {
    int i = blockIdx.x * blockDim.x + threadIdx.x;
    if (i >= n4) return;
    float4 v = reinterpret_cast<const float4*>(in)[i];
    ushort4v o;
    o.x = f2bf(v.x); o.y = f2bf(v.y); o.z = f2bf(v.z); o.w = f2bf(v.w);
    reinterpret_cast<ushort4v*>(out)[i] = o;
}

// ---------------------------------------------------------------------------
// Pre-convert the 12 64x64 weight matrices into transposed bf16 hi/lo planes:
// Bt[m][n][k] = B_m[k][n]. B-frags become contiguous 16 B global loads.
// m: 0=root1, 1-4=basis1, 5=root2, 6-9=basis2, 10=W1[0:64], 11=W1[64:128].
__global__ void prep_w(const float* __restrict__ root1, const float* __restrict__ basis1,
                       const float* __restrict__ root2, const float* __restrict__ basis2,
                       const float* __restrict__ W1,
                       unsigned short* __restrict__ Bth, unsigned short* __restrict__ Btl) {
    int idx = blockIdx.x * 256 + threadIdx.x;
    if (idx >= 12 * 4096) return;
    int m = idx >> 12;
    int nk = idx & 4095;
    int n = nk >> 6, k = nk & 63;
    const float* srcm;
    if (m == 0) srcm = root1;
    else if (m <= 4) srcm = basis1 + (size_t)(m - 1) * 4096;
    else if (m == 5) srcm = root2;
    else if (m <= 9) srcm = basis2 + (size_t)(m - 6) * 4096;
    else srcm = W1 + (size_t)(m - 10) * 4096;
    float v = srcm[k * 64 + n];
    unsigned short h = f2bf(v);
    Bth[idx] = h;
    Btl[idx] = f2bf(v - bf2f(h));
}

// ---------------------------------------------------------------------------
// Phase 1: partition edges into 196 bins by dst>>9. Record = src | et<<17 |
// dstlocal<<20 (29 bits, 4 B). LDS histogram -> one global atomic per bin.
__global__ void bin_kernel(const int* __restrict__ src, const int* __restrict__ dst,
                           const int* __restrict__ et, int* __restrict__ bin_cursor,
                           unsigned* __restrict__ ebin) {
    __shared__ int lcount[NBIN];
    __shared__ int lbase[NBIN];
    int tid = threadIdx.x;
    for (int i = tid; i < NBIN; i += 256) lcount[i] = 0;
    __syncthreads();

    int e0 = blockIdx.x * EPB;
    unsigned rec[16];
    int rnk[16];
    int bn[16];
#pragma unroll
    for (int j = 0; j < 16; ++j) {
        int e = e0 + j * 256 + tid;
        if (e < EE) {
            int d = dst[e];
            int b = d >> 9;
            bn[j] = b;
            rec[j] = (unsigned)src[e] | ((unsigned)et[e] << 17) | ((unsigned)(d & 511) << 20);
            rnk[j] = atomicAdd(&lcount[b], 1);
        } else {
            rnk[j] = -1;
        }
    }
    __syncthreads();
    for (int i = tid; i < NBIN; i += 256) lbase[i] = atomicAdd(&bin_cursor[i], lcount[i]);
    __syncthreads();
#pragma unroll
    for (int j = 0; j < 16; ++j) {
        if (rnk[j] >= 0) {
            int pos = lbase[bn[j]] + rnk[j];
            if (pos < BINCAP) ebin[(size_t)bn[j] * BINCAP + pos] = rec[j];
        }
    }
}

// Phase 2: ONE block per bin. Ranks via LDS atomics; the block's 128 KB epack
// region stays L2-resident. cnt written coalesced from LDS at the end.
__global__ __launch_bounds__(1024) void bucket_kernel(
    const unsigned* __restrict__ ebin, const int* __restrict__ bin_cursor,
    int* __restrict__ cnt, unsigned* __restrict__ epack) {
    __shared__ int lcnt[512];
    int bin = blockIdx.x;
    int tid = threadIdx.x;
    for (int i = tid; i < 512; i += 1024) lcnt[i] = 0;
    __syncthreads();

    int m = bin_cursor[bin];
    if (m > BINCAP) m = BINCAP;
    const unsigned* base = ebin + (size_t)bin * BINCAP;
    int nodebase = bin << 9;

    for (int i = tid; i < m; i += 1024) {
        unsigned rec = base[i];
        int dl = rec >> 20;
        int r = atomicAdd(&lcnt[dl], 1);
        if (r < CAP)
            epack[(size_t)(nodebase + dl) * CAP + r] = rec & 0xFFFFFu;  // src | et<<17
    }
    __syncthreads();
    for (int i = tid; i < 512; i += 1024) {
        int n = nodebase + i;
        if (n < NN) cnt[n] = lcnt[i];
    }
}

// ---------------------------------------------------------------------------
#define MFMA6(AH0, AH1, AL0, AL1, BH0, BH1, BL0, BL1, A)                          \
    A = __builtin_amdgcn_mfma_f32_16x16x32_bf16(AH0, BH0, A, 0, 0, 0);            \
    A = __builtin_amdgcn_mfma_f32_16x16x32_bf16(AH1, BH1, A, 0, 0, 0);            \
    A = __builtin_amdgcn_mfma_f32_16x16x32_bf16(AH0, BL0, A, 0, 0, 0);            \
    A = __builtin_amdgcn_mfma_f32_16x16x32_bf16(AH1, BL1, A, 0, 0, 0);            \
    A = __builtin_amdgcn_mfma_f32_16x16x32_bf16(AL0, BH0, A, 0, 0, 0);            \
    A = __builtin_amdgcn_mfma_f32_16x16x32_bf16(AL1, BH1, A, 0, 0, 0);

#define MFMA4(AH0, AH1, BH0, BH1, BL0, BL1, A)                                    \
    A = __builtin_amdgcn_mfma_f32_16x16x32_bf16(AH0, BH0, A, 0, 0, 0);            \
    A = __builtin_amdgcn_mfma_f32_16x16x32_bf16(AH1, BH1, A, 0, 0, 0);            \
    A = __builtin_amdgcn_mfma_f32_16x16x32_bf16(AH0, BL0, A, 0, 0, 0);            \
    A = __builtin_amdgcn_mfma_f32_16x16x32_bf16(AH1, BL1, A, 0, 0, 0);

// ---------------------------------------------------------------------------
// Fused per-layer kernel, M=32 tile: gather-aggregate into LDS ys (16.9 KB),
// then MFMA transform with 2x2 wave M/N split. B-frags from pre-prepped global
// (no B LDS staging, no stage_b bank conflicts, one barrier).
// XSPLIT=0: root chunk A from f32 xf. XSPLIT=1: from bf16 planes xh/xl.
// PROJ=0: out = bf16 hi/lo planes (o1,o2), optional ReLU.
// PROJ=1: z -> W1 halves (Wth/Wtl), o1=ha, o2=hb.
template <int RELU, int PROJ, int XSPLIT>
__global__ __launch_bounds__(256, 6) void rgcn_layer(
    const unsigned short* __restrict__ xg, const float* __restrict__ xf,
    const unsigned short* __restrict__ xh, const unsigned short* __restrict__ xl,
    const unsigned* __restrict__ epack, const int* __restrict__ cnt,
    const float* __restrict__ comp,
    const unsigned short* __restrict__ Bth, const unsigned short* __restrict__ Btl,
    const unsigned short* __restrict__ Wth, const unsigned short* __restrict__ Wtl,
    const float* __restrict__ bias,
    unsigned short* __restrict__ o1, unsigned short* __restrict__ o2) {
    __shared__ unsigned short ys[32 * YSTRIDE];  // 16.9 KB
    __shared__ float wlds[4 * 32];

    int tid = threadIdx.x;
    int lane = tid & 63;
    int wid = tid >> 6;
    int ln15 = lane & 15;
    int half = lane >> 5;
    int fl = lane & 31;
    int blockM = blockIdx.x * 32;

    // ---- gather-aggregate phase: 8 nodes per wave -> ys rows ----
    unsigned* ys32 = reinterpret_cast<unsigned*>(ys);
    for (int j = 0; j < 8; ++j) {
        int nl = wid * 8 + j;
        int n = blockM + nl;
        int m = cnt[n];
        if (m > CAP) m = CAP;

        unsigned pl = (lane < m) ? epack[(size_t)n * CAP + lane] : 0u;
        int et_l = (int)(pl >> 17);

        int cr0 = __popcll(__ballot((lane < m) && (et_l == 0)));
        int cr1 = __popcll(__ballot((lane < m) && (et_l == 1)));
        int cr2 = __popcll(__ballot((lane < m) && (et_l == 2)));
        int cr3 = __popcll(__ballot((lane < m) && (et_l == 3)));
        int cr4 = __popcll(__ballot((lane < m) && (et_l == 4)));
        int cr5 = __popcll(__ballot((lane < m) && (et_l == 5)));
        int cr6 = __popcll(__ballot((lane < m) && (et_l == 6)));
        int cr7 = __popcll(__ballot((lane < m) && (et_l == 7)));

        if (lane < 32) {
            int r = lane >> 2;
            int myc = cr0;
            myc = (r == 1) ? cr1 : myc;
            myc = (r == 2) ? cr2 : myc;
            myc = (r == 3) ? cr3 : myc;
            myc = (r == 4) ? cr4 : myc;
            myc = (r == 5) ? cr5 : myc;
            myc = (r == 6) ? cr6 : myc;
            myc = (r == 7) ? cr7 : myc;
            wlds[wid * 32 + lane] = comp[lane] / fmaxf((float)myc, 1.f);
        }
        // wave-synchronous LDS write->read (compiler emits lgkmcnt wait)

        float a0x = 0.f, a0y = 0.f, a1x = 0.f, a1y = 0.f;
        float a2x = 0.f, a2y = 0.f, a3x = 0.f, a3y = 0.f;

        int k = 0;
        for (; k + 4 <= m; k += 4) {
            unsigned pA = __shfl(pl, k + half);
            unsigned pB = __shfl(pl, k + 2 + half);
            unsigned rA = *reinterpret_cast<const unsigned*>(
                xg + (size_t)(pA & 0x1FFFFu) * 64 + fl * 2);
            unsigned rB = *reinterpret_cast<const unsigned*>(
                xg + (size_t)(pB & 0x1FFFFu) * 64 + fl * 2);
            float4 wA = *reinterpret_cast<const float4*>(&wlds[wid * 32 + (pA >> 17) * 4]);
            float4 wB = *reinterpret_cast<const float4*>(&wlds[wid * 32 + (pB >> 17) * 4]);
            float rAx = bf2f((unsigned short)(rA & 0xFFFF));
            float rAy = bf2f((unsigned short)(rA >> 16));
            float rBx = bf2f((unsigned short)(rB & 0xFFFF));
            float rBy = bf2f((unsigned short)(rB >> 16));
            a0x = fmaf(wA.x, rAx, a0x); a0y = fmaf(wA.x, rAy, a0y);
            a1x = fmaf(wA.y, rAx, a1x); a1y = fmaf(wA.y, rAy, a1y);
            a2x = fmaf(wA.z, rAx, a2x); a2y = fmaf(wA.z, rAy, a2y);
            a3x = fmaf(wA.w, rAx, a3x); a3y = fmaf(wA.w, rAy, a3y);
            a0x = fmaf(wB.x, rBx, a0x); a0y = fmaf(wB.x, rBy, a0y);
            a1x = fmaf(wB.y, rBx, a1x); a1y = fmaf(wB.y, rBy, a1y);
            a2x = fmaf(wB.z, rBx, a2x); a2y = fmaf(wB.z, rBy, a2y);
            a3x = fmaf(wB.w, rBx, a3x); a3y = fmaf(wB.w, rBy, a3y);
        }
        for (; k < m; k += 2) {
            int ki = k + half;
            int kc = (ki < m) ? ki : k;
            float sc = (ki < m) ? 1.f : 0.f;
            unsigned p = __shfl(pl, kc);
            unsigned rv = *reinterpret_cast<const unsigned*>(
                xg + (size_t)(p & 0x1FFFFu) * 64 + fl * 2);
            float4 wv = *reinterpret_cast<const float4*>(&wlds[wid * 32 + (p >> 17) * 4]);
            float rx = bf2f((unsigned short)(rv & 0xFFFF)) * sc;
            float ry = bf2f((unsigned short)(rv >> 16)) * sc;
            a0x = fmaf(wv.x, rx, a0x); a0y = fmaf(wv.x, ry, a0y);
            a1x = fmaf(wv.y, rx, a1x); a1y = fmaf(wv.y, ry, a1y);
            a2x = fmaf(wv.z, rx, a2x); a2y = fmaf(wv.z, ry, a2y);
            a3x = fmaf(wv.w, rx, a3x); a3y = fmaf(wv.w, ry, a3y);
        }

        a0x += __shfl_xor(a0x, 32); a0y += __shfl_xor(a0y, 32);
        a1x += __shfl_xor(a1x, 32); a1y += __shfl_xor(a1y, 32);
        a2x += __shfl_xor(a2x, 32); a2y += __shfl_xor(a2y, 32);
        a3x += __shfl_xor(a3x, 32); a3y += __shfl_xor(a3y, 32);

        float sLx = half ? a2x : a0x, sLy = half ? a2y : a0y;
        float sHx = half ? a3x : a1x, sHy = half ? a3y : a1y;
        unsigned pL = (unsigned)f2bf(sLx) | ((unsigned)f2bf(sLy) << 16);
        unsigned pH = (unsigned)f2bf(sHx) | ((unsigned)f2bf(sHy) << 16);
        ys32[nl * (YSTRIDE / 2) + (half * 2) * 32 + fl] = pL;
        ys32[nl * (YSTRIDE / 2) + (half * 2 + 1) * 32 + fl] = pH;
    }

    // ---- MFMA phase: 2x2 wave split (wm = rows 16, wn = cols 32) ----
    int wm = wid >> 1;
    int wn = wid & 1;
    int wr = wm * 16;
    int arow = wr + ln15;
    int kb = (lane >> 4) * 8;
    int bc0 = wn * 32 + ln15;

    // root-chunk A frags direct from global
    short8 xah0, xah1, xal0, xal1;
    {
        int gr = blockM + arow;
        if (XSPLIT) {
            xah0 = *reinterpret_cast<const short8*>(xh + (size_t)gr * 64 + kb);
            xah1 = *reinterpret_cast<const short8*>(xh + (size_t)gr * 64 + 32 + kb);
            xal0 = *reinterpret_cast<const short8*>(xl + (size_t)gr * 64 + kb);
            xal1 = *reinterpret_cast<const short8*>(xl + (size_t)gr * 64 + 32 + kb);
        } else {
            split8(xf + (size_t)gr * 64 + kb, xah0, xal0);
            split8(xf + (size_t)gr * 64 + 32 + kb, xah1, xal1);
        }
    }

    __syncthreads();  // ys visible

    f32x4 acc0, acc1;
    {
        float bv0 = bias[bc0];
        float bv1 = bias[bc0 + 16];
        acc0 = (f32x4){bv0, bv0, bv0, bv0};
        acc1 = (f32x4){bv1, bv1, bv1, bv1};
    }

    // chunk 0: x @ root (mat 0), full bf16x3
    {
        short8 bh0, bh1, bl0, bl1;
        load_bfrag(Bth + bc0 * 64 + kb, bh0, bh1);
        load_bfrag(Btl + bc0 * 64 + kb, bl0, bl1);
        MFMA6(xah0, xah1, xal0, xal1, bh0, bh1, bl0, bl1, acc0)
        load_bfrag(Bth + (bc0 + 16) * 64 + kb, bh0, bh1);
        load_bfrag(Btl + (bc0 + 16) * 64 + kb, bl0, bl1);
        MFMA6(xah0, xah1, xal0, xal1, bh0, bh1, bl0, bl1, acc1)
    }

    // chunks 1..4: y_b @ basis_b (mats 1..4), A hi only
#pragma unroll
    for (int c = 0; c < 4; ++c) {
        short8 ah0 = *reinterpret_cast<const short8*>(&ys[arow * YSTRIDE + c * 64 + kb]);
        short8 ah1 = *reinterpret_cast<const short8*>(&ys[arow * YSTRIDE + c * 64 + 32 + kb]);
        const unsigned short* bthc = Bth + (size_t)(c + 1) * 4096;
        const unsigned short* btlc = Btl + (size_t)(c + 1) * 4096;
        short8 bh0, bh1, bl0, bl1;
        load_bfrag(bthc + bc0 * 64 + kb, bh0, bh1);
        load_bfrag(btlc + bc0 * 64 + kb, bl0, bl1);
        MFMA4(ah0, ah1, bh0, bh1, bl0, bl1, acc0)
        load_bfrag(bthc + (bc0 + 16) * 64 + kb, bh0, bh1);
        load_bfrag(btlc + (bc0 + 16) * 64 + kb, bl0, bl1);
        MFMA4(ah0, ah1, bh0, bh1, bl0, bl1, acc1)
    }

    if (!PROJ) {
        // D mapping (m89): col = lane&15, row = (lane>>4)*4 + i
#pragma unroll
        for (int i = 0; i < 4; ++i) {
            int gr = blockM + wr + (lane >> 4) * 4 + i;
            float v0 = acc0[i];
            if (RELU) v0 = fmaxf(v0, 0.f);
            unsigned short h0v = f2bf(v0);
            o1[(size_t)gr * 64 + bc0] = h0v;
            o2[(size_t)gr * 64 + bc0] = f2bf(v0 - bf2f(h0v));
            float v1 = acc1[i];
            if (RELU) v1 = fmaxf(v1, 0.f);
            unsigned short h1v = f2bf(v1);
            o1[(size_t)gr * 64 + bc0 + 16] = h1v;
            o2[(size_t)gr * 64 + bc0 + 16] = f2bf(v1 - bf2f(h1v));
        }
    } else {
        // z hi/lo staged into the now-dead ys region (2 x 32 x 72 shorts = 9 KB)
        unsigned short* Zh = ys;
        unsigned short* Zl = ys + 32 * 72;
        __syncthreads();  // all waves done reading ys
#pragma unroll
        for (int i = 0; i < 4; ++i) {
            int r = wr + (lane >> 4) * 4 + i;
            float v0 = acc0[i];
            unsigned short h0v = f2bf(v0);
            Zh[r * 72 + bc0] = h0v;
            Zl[r * 72 + bc0] = f2bf(v0 - bf2f(h0v));
            float v1 = acc1[i];
            unsigned short h1v = f2bf(v1);
            Zh[r * 72 + bc0 + 16] = h1v;
            Zl[r * 72 + bc0 + 16] = f2bf(v1 - bf2f(h1v));
        }
        __syncthreads();
        short8 zh0 = *reinterpret_cast<const short8*>(&Zh[arow * 72 + kb]);
        short8 zh1 = *reinterpret_cast<const short8*>(&Zh[arow * 72 + 32 + kb]);
        short8 zl0 = *reinterpret_cast<const short8*>(&Zl[arow * 72 + kb]);
        short8 zl1 = *reinterpret_cast<const short8*>(&Zl[arow * 72 + 32 + kb]);
#pragma unroll
        for (int hh = 0; hh < 2; ++hh) {
            const unsigned short* wth = Wth + (size_t)hh * 4096;
            const unsigned short* wtl = Wtl + (size_t)hh * 4096;
            f32x4 a0 = (f32x4){0.f, 0.f, 0.f, 0.f};
            f32x4 a1 = (f32x4){0.f, 0.f, 0.f, 0.f};
            short8 bh0, bh1, bl0, bl1;
            load_bfrag(wth + bc0 * 64 + kb, bh0, bh1);
            load_bfrag(wtl + bc0 * 64 + kb, bl0, bl1);
            MFMA6(zh0, zh1, zl0, zl1, bh0, bh1, bl0, bl1, a0)
            load_bfrag(wth + (bc0 + 16) * 64 + kb, bh0, bh1);
            load_bfrag(wtl + (bc0 + 16) * 64 + kb, bl0, bl1);
            MFMA6(zh0, zh1, zl0, zl1, bh0, bh1, bl0, bl1, a1)
            unsigned short* oo = hh ? o2 : o1;
#pragma unroll
            for (int i = 0; i < 4; ++i) {
                int gr = blockM + wr + (lane >> 4) * 4 + i;
                oo[(size_t)gr * 64 + bc0] = f2bf(a0[i]);
                oo[(size_t)gr * 64 + bc0 + 16] = f2bf(a1[i]);
            }
        }
    }
}

// ---------------------------------------------------------------------------
// decode: 8 pairs per wave. lane = (pg = lane>>3, fg = lane&7);
// lane loads uint4 (8 bf16) of ha[a] and hb[b] at features fg*8..fg*8+7,
// per-lane partial dot, 3-step shfl reduce over the 8 fg lanes.
__global__ void decode_kernel(const int* __restrict__ pairs,
                              const unsigned short* __restrict__ ha,
                              const unsigned short* __restrict__ hb,
                              const float* __restrict__ b1, const float* __restrict__ W2,
                              const float* __restrict__ b2, float* __restrict__ out) {
    int lane = threadIdx.x & 63;
    int wid = threadIdx.x >> 6;
    int wpair0 = (blockIdx.x * 4 + wid) * 8;  // first pair of this wave
    int pg = lane >> 3;
    int fg = lane & 7;

    int pv = 0;
    if (lane < 16) pv = pairs[(size_t)wpair0 * 2 + lane];
    int a = __shfl(pv, pg * 2);
    int b = __shfl(pv, pg * 2 + 1);

    const float4* b1p = reinterpret_cast<const float4*>(b1 + fg * 8);
    float4 b1a = b1p[0], b1b = b1p[1];
    const float4* w2p = reinterpret_cast<const float4*>(W2 + fg * 8);
    float4 w2a = w2p[0], w2b = w2p[1];

    uint4 hau = *reinterpret_cast<const uint4*>(ha + (size_t)a * 64 + fg * 8);
    uint4 hbu = *reinterpret_cast<const uint4*>(hb + (size_t)b * 64 + fg * 8);

    float s = 0.f;
    s += fmaxf(bf2f((unsigned short)(hau.x & 0xFFFF)) + bf2f((unsigned short)(hbu.x & 0xFFFF)) + b1a.x, 0.f) * w2a.x;
    s += fmaxf(bf2f((unsigned short)(hau.x >> 16))    + bf2f((unsigned short)(hbu.x >> 16))    + b1a.y, 0.f) * w2a.y;
    s += fmaxf(bf2f((unsigned short)(hau.y & 0xFFFF)) + bf2f((unsigned short)(hbu.y & 0xFFFF)) + b1a.z, 0.f) * w2a.z;
    s += fmaxf(bf2f((unsigned short)(hau.y >> 16))    + bf2f((unsigned short)(hbu.y >> 16))    + b1a.w, 0.f) * w2a.w;
    s += fmaxf(bf2f((unsigned short)(hau.z & 0xFFFF)) + bf2f((unsigned short)(hbu.z & 0xFFFF)) + b1b.x, 0.f) * w2b.x;
    s += fmaxf(bf2f((unsigned short)(hau.z >> 16))    + bf2f((unsigned short)(hbu.z >> 16))    + b1b.y, 0.f) * w2b.y;
    s += fmaxf(bf2f((unsigned short)(hau.w & 0xFFFF)) + bf2f((unsigned short)(hbu.w & 0xFFFF)) + b1b.z, 0.f) * w2b.z;
    s += fmaxf(bf2f((unsigned short)(hau.w >> 16))    + bf2f((unsigned short)(hbu.w >> 16))    + b1b.w, 0.f) * w2b.w;

    s += __shfl_xor(s, 1);
    s += __shfl_xor(s, 2);
    s += __shfl_xor(s, 4);
    if (fg == 0) out[wpair0 + pg] = s + b2[0];
}

// ---------------------------------------------------------------------------
static inline char* align64(char* p) {
    return (char*)(((uintptr_t)p + 63) & ~(uintptr_t)63);
}

extern "C" void kernel_launch(void* const* d_in, const int* in_sizes, int n_in,
                              void* d_out, int out_size, void* d_ws, size_t ws_size,
                              hipStream_t stream) {
    const int* edge_index = (const int*)d_in[0];
    const int* edge_type  = (const int*)d_in[1];
    const int* edge_pairs = (const int*)d_in[2];
    const float* node_emb = (const float*)d_in[3];
    const float* comp1 = (const float*)d_in[4];
    const float* basis1 = (const float*)d_in[5];
    const float* root1 = (const float*)d_in[6];
    const float* bias1 = (const float*)d_in[7];
    const float* comp2 = (const float*)d_in[8];
    const float* basis2 = (const float*)d_in[9];
    const float* root2 = (const float*)d_in[10];
    const float* bias2 = (const float*)d_in[11];
    const float* W1 = (const float*)d_in[12];
    const float* b1 = (const float*)d_in[13];
    const float* W2 = (const float*)d_in[14];
    const float* b2 = (const float*)d_in[15];

    const int* src = edge_index;
    const int* dst = edge_index + EE;

    // workspace layout (all regions 64B-aligned)
    char* w = (char*)d_ws;
    int* bin_cursor = (int*)w;            w = align64(w + sizeof(int) * NBIN);
    int* cnt        = (int*)w;            w = align64(w + sizeof(int) * NN);
    unsigned* ebin  = (unsigned*)w;       w = align64(w + sizeof(unsigned) * (size_t)NBIN * BINCAP);
    unsigned* epack = (unsigned*)w;       w = align64(w + sizeof(unsigned) * (size_t)NN * CAP);
    unsigned short* xemb = (unsigned short*)w; w = align64(w + sizeof(short) * (size_t)NN * 64);
    unsigned short* x1h  = (unsigned short*)w; w = align64(w + sizeof(short) * (size_t)NN * 64);
    unsigned short* x1l  = (unsigned short*)w; w = align64(w + sizeof(short) * (size_t)NN * 64);
    unsigned short* hab  = (unsigned short*)w; w = align64(w + sizeof(short) * (size_t)NN * 64);
    unsigned short* hbb  = (unsigned short*)w; w = align64(w + sizeof(short) * (size_t)NN * 64);
    unsigned short* Bth  = (unsigned short*)w; w = align64(w + sizeof(short) * 12 * 4096);
    unsigned short* Btl  = (unsigned short*)w; w = align64(w + sizeof(short) * 12 * 4096);

    // ---- CSR build: bin by dst>>9, then one block per bin with LDS ranks ----
    hipMemsetAsync(bin_cursor, 0, sizeof(int) * NBIN, stream);
    bin_kernel<<<(EE + EPB - 1) / EPB, 256, 0, stream>>>(src, dst, edge_type, bin_cursor, ebin);
    bucket_kernel<<<NBIN, 1024, 0, stream>>>(ebin, bin_cursor, cnt, epack);
    tobf16_kernel<<<(NN * 16 + 255) / 256, 256, 0, stream>>>(node_emb, xemb, NN * 16);
    prep_w<<<(12 * 4096 + 255) / 256, 256, 0, stream>>>(root1, basis1, root2, basis2, W1,
                                                        Bth, Btl);

    // ---- layer 1 (fused): node_emb -> x1 hi/lo (relu) ----
    rgcn_layer<1, 0, 0><<<NN / 32, 256, 0, stream>>>(
        xemb, node_emb, nullptr, nullptr, epack, cnt, comp1,
        Bth, Btl, nullptr, nullptr, bias1, x1h, x1l);

    // ---- layer 2 (fused, + decoder projection): x1 -> ha/hb (bf16) ----
    rgcn_layer<0, 1, 1><<<NN / 32, 256, 0, stream>>>(
        x1h, nullptr, x1h, x1l, epack, cnt, comp2,
        Bth + 5 * 4096, Btl + 5 * 4096, Bth + 10 * 4096, Btl + 10 * 4096,
        bias2, hab, hbb);

    // ---- decoder ----
    decode_kernel<<<PP / 32, 256, 0, stream>>>(edge_pairs, hab, hbb, b1, W2, b2, (float*)d_out);
}